// Round 6
// baseline (332.648 us; speedup 1.0000x reference)
//
#include <hip/hip_runtime.h>
#include <hip/hip_cooperative_groups.h>
#include <math.h>

namespace cg = cooperative_groups;

#define T_ 128
#define NPROJ 2176  // cols: [0,512)=Q [512,1024)=K [1024,1536)=V [1536,1600)=beta [1600,1664)=tg [1664,2176)=gate
#define CH 32       // scan chunk

typedef __attribute__((ext_vector_type(8))) short short8;
typedef __attribute__((ext_vector_type(4))) float float4v;
typedef __attribute__((ext_vector_type(2))) float float2v;

__device__ __forceinline__ ushort f2bf(float x) {
    unsigned u = __float_as_uint(x);
    u += 0x7FFF + ((u >> 16) & 1);   // RNE
    return (ushort)(u >> 16);
}

template<int CTRL>
__device__ __forceinline__ float dpp_add(float x) {
    int xi = __float_as_int(x);
    int yi = __builtin_amdgcn_update_dpp(xi, xi, CTRL, 0xF, 0xF, false);
    return x + __int_as_float(yi);
}

struct KParams {
    const float *x, *Wq, *Wk, *Wv, *Wb, *Wtg, *ml, *ldc, *ols, *Wg, *Wo;
    float *cosw, *sinw, *rho, *modew, *proj, *Acomb, *out;
    ushort *xb, *wtb, *wotb;
};

struct SmemGemm { ushort sA[2][64][40]; ushort sB[2][64][40]; };            // 20480 B
struct SmemScan { float qk[2][CH][128]; float vbuf[2][CH][16];
                  float gbuf[2][CH][16]; float sc4[2][CH][4]; };            // 41984 B
struct SmemPrep { ushort tile[64][68]; };                                   // 8704 B
union Smem { SmemGemm g; SmemScan s; SmemPrep p; };

__global__ __launch_bounds__(256, 2) void mega_kernel(KParams P)
{
    __shared__ Smem sm;
    cg::grid_group grid = cg::this_grid();
    const int blk = blockIdx.x;       // 512 blocks
    const int tid = threadIdx.x;      // 256 threads

    // ======================= Phase 0: prep (784 units over 512 blocks) ================
    for (int u = blk; u < 784; u += 512) {
        __syncthreads();   // protect tile reuse across units
        if (u < 16) {
            int idx = u * 256 + tid;
            if (idx < 64 * 64) {
                int t = idx >> 6;   // hr
                int k = idx & 63;
                int h = t >> 3;
                if (k == 0) {
                    float ld = P.ldc[t];
                    P.rho[t] = 1.0f / (1.0f + expf(ld));  // exp(-softplus) == sigmoid(-x)
                    float m = -1e30f;
                    for (int i = 0; i < 8; i++) m = fmaxf(m, P.ml[h * 8 + i]);
                    float sum = 0.0f;
                    for (int i = 0; i < 8; i++) sum += expf(P.ml[h * 8 + i] - m);
                    P.modew[t] = expf(P.ml[t] - m) / sum;
                }
                float osc = expf(P.ols[t]);
                int p = k >> 1;
                float invf = expf(-((float)(2 * p) / 64.0f) * logf(10000.0f));
                float w = osc * invf;
                P.cosw[idx] = cosf(w);
                P.sinw[idx] = sinf(w);
            }
        } else if (u < 80) {   // x -> bf16
            int base = (u - 16) * 4096 + tid * 16;
            float4 f0 = *(const float4*)&P.x[base];
            float4 f1 = *(const float4*)&P.x[base + 4];
            float4 f2 = *(const float4*)&P.x[base + 8];
            float4 f3 = *(const float4*)&P.x[base + 12];
            short8 o0, o1;
            o0[0]=f2bf(f0.x); o0[1]=f2bf(f0.y); o0[2]=f2bf(f0.z); o0[3]=f2bf(f0.w);
            o0[4]=f2bf(f1.x); o0[5]=f2bf(f1.y); o0[6]=f2bf(f1.z); o0[7]=f2bf(f1.w);
            o1[0]=f2bf(f2.x); o1[1]=f2bf(f2.y); o1[2]=f2bf(f2.z); o1[3]=f2bf(f2.w);
            o1[4]=f2bf(f3.x); o1[5]=f2bf(f3.y); o1[6]=f2bf(f3.z); o1[7]=f2bf(f3.w);
            *(short8*)&P.xb[base] = o0;
            *(short8*)&P.xb[base + 8] = o1;
        } else if (u < 752) {  // W / Wo transpose-convert
            const float* src; int ld, c0, n0, k0, ldd; ushort* dst;
            if (u < 624) {
                int b3 = u - 80; int nt = b3 >> 4, kt = b3 & 15;
                n0 = nt * 64; k0 = kt * 64;
                if (n0 < 512)       { src = P.Wq;  c0 = n0;        ld = 512; }
                else if (n0 < 1024) { src = P.Wk;  c0 = n0 - 512;  ld = 512; }
                else if (n0 < 1536) { src = P.Wv;  c0 = n0 - 1024; ld = 512; }
                else if (n0 < 1600) { src = P.Wb;  c0 = n0 - 1536; ld = 64;  }
                else if (n0 < 1664) { src = P.Wtg; c0 = n0 - 1600; ld = 64;  }
                else                { src = P.Wg;  c0 = n0 - 1664; ld = 512; }
                dst = P.wtb; ldd = 1024;
            } else {
                int b4 = u - 624; int nt = b4 >> 3, kt = b4 & 7;
                n0 = nt * 64; k0 = kt * 64;
                src = P.Wo; c0 = n0; ld = 1024; dst = P.wotb; ldd = 512;
            }
            #pragma unroll
            for (int rep = 0; rep < 4; rep++) {
                int k = rep * 16 + (tid >> 4);
                int nc = (tid & 15) * 4;
                float4 f = *(const float4*)&src[(size_t)(k0 + k) * ld + c0 + nc];
                sm.p.tile[nc + 0][k] = f2bf(f.x);
                sm.p.tile[nc + 1][k] = f2bf(f.y);
                sm.p.tile[nc + 2][k] = f2bf(f.z);
                sm.p.tile[nc + 3][k] = f2bf(f.w);
            }
            __syncthreads();
            #pragma unroll
            for (int rep = 0; rep < 4; rep++) {
                int n = rep * 16 + (tid >> 4);
                int kc = (tid & 15) * 4;
                uint2 uu = *(const uint2*)&sm.p.tile[n][kc];
                *(uint2*)&dst[(size_t)(n0 + n) * ldd + k0 + kc] = uu;
            }
        } else {               // zero Acomb
            int base = (u - 752) * 4096 + tid * 16;
            float4 z = make_float4(0.f, 0.f, 0.f, 0.f);
            *(float4*)&P.Acomb[base] = z;
            *(float4*)&P.Acomb[base + 4] = z;
            *(float4*)&P.Acomb[base + 8] = z;
            *(float4*)&P.Acomb[base + 12] = z;
        }
    }
    grid.sync();

    // ======================= Phase 1: proj GEMM (blocks 0..135) =======================
    if (blk < 136) {
        const int n0 = (blk % 34) * 64, m0 = (blk / 34) * 64;
        const int lane = tid & 63, w = tid >> 6;
        const int wm = w & 1, wn = w >> 1;
        const int l16 = lane & 15, quad = lane >> 4;
        const int srow = tid >> 2, skq = (tid & 3) * 8;
        const ushort* Ag = P.xb + (size_t)(m0 + srow) * 1024 + skq;
        const ushort* Bg = P.wtb + (size_t)(n0 + srow) * 1024 + skq;
        short8 ra = *(const short8*)Ag;
        short8 rb = *(const short8*)Bg;
        float4v acc00 = {0,0,0,0}, acc01 = {0,0,0,0}, acc10 = {0,0,0,0}, acc11 = {0,0,0,0};
        for (int kt = 0; kt < 32; kt++) {
            const int cb = kt & 1;
            *(short8*)&sm.g.sA[cb][srow][skq] = ra;
            *(short8*)&sm.g.sB[cb][srow][skq] = rb;
            __syncthreads();
            if (kt + 1 < 32) {
                ra = *(const short8*)(Ag + (kt + 1) * 32);
                rb = *(const short8*)(Bg + (kt + 1) * 32);
            }
            short8 a0 = *(const short8*)&sm.g.sA[cb][wm * 32 + l16][quad * 8];
            short8 a1 = *(const short8*)&sm.g.sA[cb][wm * 32 + 16 + l16][quad * 8];
            short8 b0 = *(const short8*)&sm.g.sB[cb][wn * 32 + l16][quad * 8];
            short8 b1 = *(const short8*)&sm.g.sB[cb][wn * 32 + 16 + l16][quad * 8];
            acc00 = __builtin_amdgcn_mfma_f32_16x16x32_bf16(a0, b0, acc00, 0, 0, 0);
            acc01 = __builtin_amdgcn_mfma_f32_16x16x32_bf16(a0, b1, acc01, 0, 0, 0);
            acc10 = __builtin_amdgcn_mfma_f32_16x16x32_bf16(a1, b0, acc10, 0, 0, 0);
            acc11 = __builtin_amdgcn_mfma_f32_16x16x32_bf16(a1, b1, acc11, 0, 0, 0);
        }
        const bool sig = (n0 >= 1536);
        const int colb = n0 + wn * 32 + l16;
        const int rowb = m0 + wm * 32 + quad * 4;
        #pragma unroll
        for (int r2 = 0; r2 < 4; r2++) {
            float v00 = acc00[r2], v01 = acc01[r2], v10 = acc10[r2], v11 = acc11[r2];
            if (sig) {
                v00 = 1.0f / (1.0f + expf(-v00));
                v01 = 1.0f / (1.0f + expf(-v01));
                v10 = 1.0f / (1.0f + expf(-v10));
                v11 = 1.0f / (1.0f + expf(-v11));
            }
            P.proj[(size_t)(rowb + r2) * NPROJ + colb] = v00;
            P.proj[(size_t)(rowb + r2) * NPROJ + colb + 16] = v01;
            P.proj[(size_t)(rowb + 16 + r2) * NPROJ + colb] = v10;
            P.proj[(size_t)(rowb + 16 + r2) * NPROJ + colb + 16] = v11;
        }
    }
    grid.sync();

    // ======================= Phase 2: scan (all 512 blocks) ===========================
    {
        const int s  = blk & 3;
        const int hr = (blk >> 2) & 63;
        const int b  = blk >> 8;
        const int h = hr >> 3, r = hr & 7;
        const int vl = tid >> 4;
        const int kl = tid & 15;

        float2v cw0, cw1, sw0, sw1;
        cw0.x = P.cosw[hr * 64 + kl * 4 + 0]; cw0.y = P.cosw[hr * 64 + kl * 4 + 1];
        cw1.x = P.cosw[hr * 64 + kl * 4 + 2]; cw1.y = P.cosw[hr * 64 + kl * 4 + 3];
        sw0.x = P.sinw[hr * 64 + kl * 4 + 0]; sw0.y = P.sinw[hr * 64 + kl * 4 + 1];
        sw1.x = P.sinw[hr * 64 + kl * 4 + 2]; sw1.y = P.sinw[hr * 64 + kl * 4 + 3];
        const float rho_hr = P.rho[hr];
        const float mw = P.modew[hr];
        float2v sr0 = {0,0}, sr1 = {0,0}, si0 = {0,0}, si1 = {0,0};

        const float* pb = P.proj + (size_t)b * T_ * NPROJ;
        const int qbase = h * 64;
        const int kbase = 512 + h * 64;
        const int vbase = 1024 + h * 64 + s * 16;
        const int gbase = 1664 + h * 64 + s * 16;
        const int boff  = 1536 + h * 8 + r;
        const int goff  = 1600 + h * 8 + r;

        auto stage = [&](int t0, int nb) {
            #pragma unroll
            for (int rep = 0; rep < 4; rep++) {
                int idx = rep * 256 + tid;
                int t = idx >> 5, sub = idx & 31;
                const float* row = pb + (size_t)(t0 + t) * NPROJ;
                float4 val = *(const float4*)(row + (sub < 16 ? qbase + sub * 4
                                                              : kbase + (sub - 16) * 4));
                *(float4*)&sm.s.qk[nb][t][sub * 4] = val;
            }
            if (tid < 128) {
                int t = tid >> 2, sub = tid & 3;
                *(float4*)&sm.s.vbuf[nb][t][sub * 4] =
                    *(const float4*)(pb + (size_t)(t0 + t) * NPROJ + vbase + sub * 4);
            } else {
                int t = (tid - 128) >> 2, sub = tid & 3;
                *(float4*)&sm.s.gbuf[nb][t][sub * 4] =
                    *(const float4*)(pb + (size_t)(t0 + t) * NPROJ + gbase + sub * 4);
            }
            if (tid < CH)            sm.s.sc4[nb][tid][0]      = pb[(size_t)(t0 + tid) * NPROJ + boff];
            else if (tid < 2 * CH)   sm.s.sc4[nb][tid - CH][1] = pb[(size_t)(t0 + tid - CH) * NPROJ + goff];
        };

        __syncthreads();   // ensure phase-1 LDS use is done before overwriting union
        stage(0, 0);
        __syncthreads();

        float* dst = P.Acomb + ((size_t)b * 128) * 512 + h * 64 + s * 16 + vl;

        for (int c = 0; c < T_ / CH; c++) {
            const int cb = c & 1;
            {   // hoisted kq_t for this chunk
                int t = tid >> 3, j = tid & 7;
                float4 ka = *(const float4*)&sm.s.qk[cb][t][64 + j * 8];
                float4 kb4 = *(const float4*)&sm.s.qk[cb][t][64 + j * 8 + 4];
                float4 qa = *(const float4*)&sm.s.qk[cb][t][j * 8];
                float4 qb4 = *(const float4*)&sm.s.qk[cb][t][j * 8 + 4];
                float p = ka.x * qa.x + ka.y * qa.y + ka.z * qa.z + ka.w * qa.w
                        + kb4.x * qb4.x + kb4.y * qb4.y + kb4.z * qb4.z + kb4.w * qb4.w;
                p = dpp_add<0xB1>(p);
                p = dpp_add<0x4E>(p);
                p = dpp_add<0x141>(p);
                if (j == 0) sm.s.sc4[cb][t][2] = p;
            }
            __syncthreads();
            if (c + 1 < T_ / CH) stage((c + 1) * CH, (c + 1) & 1);

            #pragma unroll 4
            for (int t = 0; t < CH; t++) {
                float4 kf = *(const float4*)&sm.s.qk[cb][t][64 + kl * 4];
                float4 qf = *(const float4*)&sm.s.qk[cb][t][kl * 4];
                float4 sv = *(const float4*)&sm.s.sc4[cb][t][0];   // beta, tg, kq
                const float vv = sm.s.vbuf[cb][t][vl];
                const float gate = sm.s.gbuf[cb][t][vl];

                const float decay = sv.y * rho_hr;
                float2v k0; k0.x = kf.x; k0.y = kf.y;
                float2v k1; k1.x = kf.z; k1.y = kf.w;
                float2v q0; q0.x = qf.x; q0.y = qf.y;
                float2v q1; q1.x = qf.z; q1.y = qf.w;

                float2v t1 = cw0 * sr0 - sw0 * si0;
                float2v u1 = sw0 * sr0 + cw0 * si0;
                float2v t2 = cw1 * sr1 - sw1 * si1;
                float2v u2 = sw1 * sr1 + cw1 * si1;
                float2v d2; d2.x = decay; d2.y = decay;
                float2v rr0 = d2 * t1, rr1 = d2 * t2;
                si0 = d2 * u1; si1 = d2 * u2;

                float2v pk2 = rr0 * k0 + rr1 * k1;
                float2v pq2 = rr0 * q0 + rr1 * q1;
                float pk = pk2.x + pk2.y;
                float pq = pq2.x + pq2.y;
                pk = dpp_add<0xB1>(pk);  pq = dpp_add<0xB1>(pq);
                pk = dpp_add<0x4E>(pk);  pq = dpp_add<0x4E>(pq);
                pk = dpp_add<0x141>(pk); pq = dpp_add<0x141>(pq);
                pk = dpp_add<0x140>(pk); pq = dpp_add<0x140>(pq);

                const float sc = sv.x * (vv - pk);
                float2v sc2; sc2.x = sc; sc2.y = sc;
                sr0 = rr0 + sc2 * k0;
                sr1 = rr1 + sc2 * k1;
                const float rp = pq + sc * sv.z;   // = sum(sr_new * q)
                if (kl == 0) atomicAdd(dst + (size_t)(c * CH + t) * 512, mw * rp * gate);
            }
            __syncthreads();
        }
    }
    grid.sync();

    // ======================= Phase 3: out GEMM (blocks 0..63) =========================
    if (blk < 64) {
        const int n0 = (blk % 16) * 64, m0 = (blk / 16) * 64;
        const int lane = tid & 63, w = tid >> 6;
        const int wm = w & 1, wn = w >> 1;
        const int l16 = lane & 15, quad = lane >> 4;
        const int srow = tid >> 2, skq = (tid & 3) * 8;
        const float* Ag = P.Acomb + (size_t)(m0 + srow) * 512 + skq;
        const ushort* Bg = P.wotb + (size_t)(n0 + srow) * 512 + skq;
        float4 fa0 = *(const float4*)Ag;
        float4 fa1 = *(const float4*)(Ag + 4);
        short8 rb = *(const short8*)Bg;
        float4v acc00 = {0,0,0,0}, acc01 = {0,0,0,0}, acc10 = {0,0,0,0}, acc11 = {0,0,0,0};
        for (int kt = 0; kt < 16; kt++) {
            const int cb = kt & 1;
            short8 ra;
            ra[0]=f2bf(fa0.x); ra[1]=f2bf(fa0.y); ra[2]=f2bf(fa0.z); ra[3]=f2bf(fa0.w);
            ra[4]=f2bf(fa1.x); ra[5]=f2bf(fa1.y); ra[6]=f2bf(fa1.z); ra[7]=f2bf(fa1.w);
            *(short8*)&sm.g.sA[cb][srow][skq] = ra;
            *(short8*)&sm.g.sB[cb][srow][skq] = rb;
            __syncthreads();
            if (kt + 1 < 16) {
                fa0 = *(const float4*)(Ag + (kt + 1) * 32);
                fa1 = *(const float4*)(Ag + (kt + 1) * 32 + 4);
                rb = *(const short8*)(Bg + (kt + 1) * 32);
            }
            short8 a0 = *(const short8*)&sm.g.sA[cb][wm * 32 + l16][quad * 8];
            short8 a1 = *(const short8*)&sm.g.sA[cb][wm * 32 + 16 + l16][quad * 8];
            short8 b0 = *(const short8*)&sm.g.sB[cb][wn * 32 + l16][quad * 8];
            short8 b1 = *(const short8*)&sm.g.sB[cb][wn * 32 + 16 + l16][quad * 8];
            acc00 = __builtin_amdgcn_mfma_f32_16x16x32_bf16(a0, b0, acc00, 0, 0, 0);
            acc01 = __builtin_amdgcn_mfma_f32_16x16x32_bf16(a0, b1, acc01, 0, 0, 0);
            acc10 = __builtin_amdgcn_mfma_f32_16x16x32_bf16(a1, b0, acc10, 0, 0, 0);
            acc11 = __builtin_amdgcn_mfma_f32_16x16x32_bf16(a1, b1, acc11, 0, 0, 0);
        }
        const int colb = n0 + wn * 32 + l16;
        const int rowb = m0 + wm * 32 + quad * 4;
        #pragma unroll
        for (int r2 = 0; r2 < 4; r2++) {
            P.out[(size_t)(rowb + r2) * 1024 + colb] = acc00[r2];
            P.out[(size_t)(rowb + r2) * 1024 + colb + 16] = acc01[r2];
            P.out[(size_t)(rowb + 16 + r2) * 1024 + colb] = acc10[r2];
            P.out[(size_t)(rowb + 16 + r2) * 1024 + colb + 16] = acc11[r2];
        }
    }
}

extern "C" void kernel_launch(void* const* d_in, const int* in_sizes, int n_in,
                              void* d_out, int out_size, void* d_ws, size_t ws_size,
                              hipStream_t stream) {
    float* ws = (float*)d_ws;
    KParams P;
    P.x   = (const float*)d_in[0];
    P.Wq  = (const float*)d_in[1];
    P.Wk  = (const float*)d_in[2];
    P.Wv  = (const float*)d_in[3];
    P.Wb  = (const float*)d_in[4];
    P.Wtg = (const float*)d_in[5];
    P.ml  = (const float*)d_in[6];
    P.ldc = (const float*)d_in[7];
    P.ols = (const float*)d_in[8];
    P.Wg  = (const float*)d_in[9];
    P.Wo  = (const float*)d_in[10];
    P.out = (float*)d_out;

    P.proj  = ws;                                    // 557056 f
    P.cosw  = P.proj + 256 * NPROJ;                  // 4096
    P.sinw  = P.cosw + 4096;                         // 4096
    P.rho   = P.sinw + 4096;                         // 64
    P.modew = P.rho + 64;                            // 64
    P.xb    = (ushort*)(P.modew + 64);               // 262144 us = 131072 f
    P.wotb  = (ushort*)((float*)P.xb + 131072);      // 524288 us = 262144 f
    P.Acomb = (float*)P.wotb + 262144;               // 131072 f
    P.wtb   = (ushort*)(P.Acomb + 131072);           // 2228224 us = 1114112 f

    void* args[] = { &P };
    hipLaunchCooperativeKernel((void*)mega_kernel, dim3(512), dim3(256),
                               args, 0, stream);
}

// Round 7
// 151.191 us; speedup vs baseline: 2.2002x; 2.2002x over previous
//
#include <hip/hip_runtime.h>
#include <math.h>

#define T_ 128
#define NPROJ 2176  // cols: [0,512)=Q [512,1024)=K [1024,1536)=V [1536,1600)=beta [1600,1664)=tg [1664,2176)=gate
#define CH 32       // scan chunk

typedef __attribute__((ext_vector_type(8))) short short8;
typedef __attribute__((ext_vector_type(4))) float float4v;
typedef __attribute__((ext_vector_type(2))) float float2v;

__device__ __forceinline__ ushort f2bf(float x) {
    unsigned u = __float_as_uint(x);
    u += 0x7FFF + ((u >> 16) & 1);   // RNE
    return (ushort)(u >> 16);
}

// scalar DPP butterfly add (16-lane reduction, used in kq hoist)
template<int CTRL>
__device__ __forceinline__ float dpp_add(float x) {
    int xi = __float_as_int(x);
    int yi = __builtin_amdgcn_update_dpp(xi, xi, CTRL, 0xF, 0xF, false);
    return x + __int_as_float(yi);
}
// paired DPP butterfly add: reduces {x,y} together, v_pk_add_f32 (3 insts/level)
template<int CTRL>
__device__ __forceinline__ float2v dpp_add2(float2v x) {
    int lo = __builtin_amdgcn_update_dpp(__float_as_int(x.x), __float_as_int(x.x), CTRL, 0xF, 0xF, false);
    int hi = __builtin_amdgcn_update_dpp(__float_as_int(x.y), __float_as_int(x.y), CTRL, 0xF, 0xF, false);
    float2v o; o.x = __int_as_float(lo); o.y = __int_as_float(hi);
    return x + o;
}
// xor-16 across the 32-lane group via ds_swizzle (BitMode xor mask 16)
__device__ __forceinline__ float2v swz16_add2(float2v x) {
    int lo = __builtin_amdgcn_ds_swizzle(__float_as_int(x.x), 0x401F);
    int hi = __builtin_amdgcn_ds_swizzle(__float_as_int(x.y), 0x401F);
    float2v o; o.x = __int_as_float(lo); o.y = __int_as_float(hi);
    return x + o;
}

// ---------------- Kernel 1: prep = params + x->bf16 + W/Wo transpose + Acomb zero -----
__global__ __launch_bounds__(256) void prep_kernel(
    const float* __restrict__ x,
    const float* __restrict__ Wq, const float* __restrict__ Wk,
    const float* __restrict__ Wv, const float* __restrict__ Wb,
    const float* __restrict__ Wtg, const float* __restrict__ Wg,
    const float* __restrict__ Wo,
    const float* __restrict__ mode_logits, const float* __restrict__ log_decay,
    const float* __restrict__ ols,
    float* __restrict__ cosw, float* __restrict__ sinw,
    float* __restrict__ rho, float* __restrict__ modew,
    ushort* __restrict__ xb, ushort* __restrict__ wtb, ushort* __restrict__ wotb,
    float* __restrict__ Acomb)
{
    __shared__ ushort tile[64][68];
    const int blk = blockIdx.x, tid = threadIdx.x;
    if (blk < 16) {
        int idx = blk * 256 + tid;
        if (idx >= 64 * 64) return;
        int t = idx >> 6;   // hr
        int k = idx & 63;
        int h = t >> 3;
        if (k == 0) {
            float ld = log_decay[t];
            rho[t] = 1.0f / (1.0f + expf(ld));  // exp(-softplus) == sigmoid(-x)
            float m = -1e30f;
            for (int i = 0; i < 8; i++) m = fmaxf(m, mode_logits[h * 8 + i]);
            float sum = 0.0f;
            for (int i = 0; i < 8; i++) sum += expf(mode_logits[h * 8 + i] - m);
            modew[t] = expf(mode_logits[t] - m) / sum;
        }
        float osc = expf(ols[t]);
        int p = k >> 1;
        float invf = expf(-((float)(2 * p) / 64.0f) * logf(10000.0f));
        float w = osc * invf;
        cosw[idx] = cosf(w);
        sinw[idx] = sinf(w);
        return;
    }
    if (blk < 80) {   // x convert
        int base = (blk - 16) * 4096 + tid * 16;
        float4 f0 = *(const float4*)&x[base];
        float4 f1 = *(const float4*)&x[base + 4];
        float4 f2 = *(const float4*)&x[base + 8];
        float4 f3 = *(const float4*)&x[base + 12];
        short8 o0, o1;
        o0[0]=f2bf(f0.x); o0[1]=f2bf(f0.y); o0[2]=f2bf(f0.z); o0[3]=f2bf(f0.w);
        o0[4]=f2bf(f1.x); o0[5]=f2bf(f1.y); o0[6]=f2bf(f1.z); o0[7]=f2bf(f1.w);
        o1[0]=f2bf(f2.x); o1[1]=f2bf(f2.y); o1[2]=f2bf(f2.z); o1[3]=f2bf(f2.w);
        o1[4]=f2bf(f3.x); o1[5]=f2bf(f3.y); o1[6]=f2bf(f3.z); o1[7]=f2bf(f3.w);
        *(short8*)&xb[base] = o0;
        *(short8*)&xb[base + 8] = o1;
        return;
    }
    if (blk >= 752) {  // zero Acomb
        int base = (blk - 752) * 4096 + tid * 16;
        float4 z = make_float4(0.f, 0.f, 0.f, 0.f);
        *(float4*)&Acomb[base] = z;
        *(float4*)&Acomb[base + 4] = z;
        *(float4*)&Acomb[base + 8] = z;
        *(float4*)&Acomb[base + 12] = z;
        return;
    }
    // transpose-convert
    const float* src; int ld, c0, n0, k0, ldd; ushort* dst;
    if (blk < 624) {
        int b3 = blk - 80; int nt = b3 >> 4, kt = b3 & 15;
        n0 = nt * 64; k0 = kt * 64;
        if (n0 < 512)       { src = Wq;  c0 = n0;        ld = 512; }
        else if (n0 < 1024) { src = Wk;  c0 = n0 - 512;  ld = 512; }
        else if (n0 < 1536) { src = Wv;  c0 = n0 - 1024; ld = 512; }
        else if (n0 < 1600) { src = Wb;  c0 = n0 - 1536; ld = 64;  }
        else if (n0 < 1664) { src = Wtg; c0 = n0 - 1600; ld = 64;  }
        else                { src = Wg;  c0 = n0 - 1664; ld = 512; }
        dst = wtb; ldd = 1024;
    } else {
        int b4 = blk - 624; int nt = b4 >> 3, kt = b4 & 7;
        n0 = nt * 64; k0 = kt * 64;
        src = Wo; c0 = n0; ld = 1024; dst = wotb; ldd = 512;
    }
    #pragma unroll
    for (int rep = 0; rep < 4; rep++) {
        int k = rep * 16 + (tid >> 4);
        int nc = (tid & 15) * 4;
        float4 f = *(const float4*)&src[(size_t)(k0 + k) * ld + c0 + nc];
        tile[nc + 0][k] = f2bf(f.x);
        tile[nc + 1][k] = f2bf(f.y);
        tile[nc + 2][k] = f2bf(f.z);
        tile[nc + 3][k] = f2bf(f.w);
    }
    __syncthreads();
    #pragma unroll
    for (int rep = 0; rep < 4; rep++) {
        int n = rep * 16 + (tid >> 4);
        int kc = (tid & 15) * 4;
        uint2 uu = *(const uint2*)&tile[n][kc];
        *(uint2*)&dst[(size_t)(n0 + n) * ldd + k0 + kc] = uu;
    }
}

// ---------------- Kernel 2: proj MFMA GEMM ---------------------------------------------
__global__ __launch_bounds__(256, 2) void proj_mfma(const ushort* __restrict__ Ab,
        const ushort* __restrict__ BTb, float* __restrict__ proj)
{
    __shared__ ushort sA[2][64][40];
    __shared__ ushort sB[2][64][40];
    const int n0 = blockIdx.x * 64, m0 = blockIdx.y * 64;
    const int tid = threadIdx.x;
    const int lane = tid & 63, w = tid >> 6;
    const int wm = w & 1, wn = w >> 1;
    const int l16 = lane & 15, quad = lane >> 4;
    const int srow = tid >> 2, skq = (tid & 3) * 8;
    const ushort* Ag = Ab + (size_t)(m0 + srow) * 1024 + skq;
    const ushort* Bg = BTb + (size_t)(n0 + srow) * 1024 + skq;
    short8 ra = *(const short8*)Ag;
    short8 rb = *(const short8*)Bg;
    float4v acc00 = {0,0,0,0}, acc01 = {0,0,0,0}, acc10 = {0,0,0,0}, acc11 = {0,0,0,0};
    for (int kt = 0; kt < 32; kt++) {
        const int cb = kt & 1;
        *(short8*)&sA[cb][srow][skq] = ra;
        *(short8*)&sB[cb][srow][skq] = rb;
        __syncthreads();
        if (kt + 1 < 32) {
            ra = *(const short8*)(Ag + (kt + 1) * 32);
            rb = *(const short8*)(Bg + (kt + 1) * 32);
        }
        short8 a0 = *(const short8*)&sA[cb][wm * 32 + l16][quad * 8];
        short8 a1 = *(const short8*)&sA[cb][wm * 32 + 16 + l16][quad * 8];
        short8 b0 = *(const short8*)&sB[cb][wn * 32 + l16][quad * 8];
        short8 b1 = *(const short8*)&sB[cb][wn * 32 + 16 + l16][quad * 8];
        acc00 = __builtin_amdgcn_mfma_f32_16x16x32_bf16(a0, b0, acc00, 0, 0, 0);
        acc01 = __builtin_amdgcn_mfma_f32_16x16x32_bf16(a0, b1, acc01, 0, 0, 0);
        acc10 = __builtin_amdgcn_mfma_f32_16x16x32_bf16(a1, b0, acc10, 0, 0, 0);
        acc11 = __builtin_amdgcn_mfma_f32_16x16x32_bf16(a1, b1, acc11, 0, 0, 0);
    }
    const bool sig = (n0 >= 1536);
    const int colb = n0 + wn * 32 + l16;
    const int rowb = m0 + wm * 32 + quad * 4;
    #pragma unroll
    for (int r2 = 0; r2 < 4; r2++) {
        float v00 = acc00[r2], v01 = acc01[r2], v10 = acc10[r2], v11 = acc11[r2];
        if (sig) {
            v00 = 1.0f / (1.0f + expf(-v00));
            v01 = 1.0f / (1.0f + expf(-v01));
            v10 = 1.0f / (1.0f + expf(-v10));
            v11 = 1.0f / (1.0f + expf(-v11));
        }
        proj[(size_t)(rowb + r2) * NPROJ + colb] = v00;
        proj[(size_t)(rowb + r2) * NPROJ + colb + 16] = v01;
        proj[(size_t)(rowb + 16 + r2) * NPROJ + colb] = v10;
        proj[(size_t)(rowb + 16 + r2) * NPROJ + colb + 16] = v11;
    }
}

// ---------------- Kernel 3: scan — 32 k-lanes x 2 elems, 512-thread blocks ------------
// grid 512 = b(2) x hr(64) x s(4); block 512: vl = tid>>5 (16 v), kl = tid&31 (2 k each)
// 4096 waves total = 4 waves/SIMD for latency hiding.
__global__ __launch_bounds__(512, 2) void scan_kernel(const float* __restrict__ proj,
        const float* __restrict__ cosw, const float* __restrict__ sinw,
        const float* __restrict__ rho, const float* __restrict__ modew,
        float* __restrict__ Acomb)
{
    __shared__ float qk[2][CH][128];     // per t: [0..63]=q, [64..127]=k
    __shared__ float2 vg[2][CH][16];     // {v, gate} per (t, vl)
    __shared__ float sc4[2][CH][4];      // [0]=beta [1]=tg [2]=kq

    const int bi = blockIdx.x;
    const int s  = bi & 3;
    const int hr = (bi >> 2) & 63;
    const int b  = bi >> 8;
    const int h = hr >> 3, r = hr & 7;
    const int tid = threadIdx.x;
    const int vl = tid >> 5;             // 0..15
    const int kl = tid & 31;             // 0..31, low 5 lane bits

    float2v cw, sw;
    cw.x = cosw[hr * 64 + kl * 2];  cw.y = cosw[hr * 64 + kl * 2 + 1];
    sw.x = sinw[hr * 64 + kl * 2];  sw.y = sinw[hr * 64 + kl * 2 + 1];
    const float rho_hr = rho[hr];
    const float mw = modew[hr];
    float2v sr = {0,0}, si = {0,0};

    const float* pb = proj + (size_t)b * T_ * NPROJ;
    const int qbase = h * 64;
    const int kbase = 512 + h * 64;
    const int vbase = 1024 + h * 64 + s * 16;
    const int gbase = 1664 + h * 64 + s * 16;
    const int boff  = 1536 + h * 8 + r;
    const int goff  = 1600 + h * 8 + r;

    auto stage = [&](int t0, int nb) {
        #pragma unroll
        for (int rep = 0; rep < 2; rep++) {
            int idx = rep * 512 + tid;
            int t = idx >> 5, sub = idx & 31;
            const float* row = pb + (size_t)(t0 + t) * NPROJ;
            float4 val = *(const float4*)(row + (sub < 16 ? qbase + sub * 4
                                                          : kbase + (sub - 16) * 4));
            *(float4*)&qk[nb][t][sub * 4] = val;
        }
        {
            int t = tid >> 4, v2 = tid & 15;
            const float* row = pb + (size_t)(t0 + t) * NPROJ;
            vg[nb][t][v2] = make_float2(row[vbase + v2], row[gbase + v2]);
        }
        if (tid < CH)            sc4[nb][tid][0]      = pb[(size_t)(t0 + tid) * NPROJ + boff];
        else if (tid < 2 * CH)   sc4[nb][tid - CH][1] = pb[(size_t)(t0 + tid - CH) * NPROJ + goff];
    };

    stage(0, 0);
    __syncthreads();

    float* dst = Acomb + ((size_t)b * 128) * 512 + h * 64 + s * 16 + vl;

    for (int c = 0; c < T_ / CH; c++) {
        const int cb = c & 1;
        {   // hoisted kq_t for this chunk: t = tid>>4, 16 lanes x 4 elems
            int t = tid >> 4, j = tid & 15;
            float4 ka = *(const float4*)&qk[cb][t][64 + j * 4];
            float4 qa = *(const float4*)&qk[cb][t][j * 4];
            float p = ka.x * qa.x + ka.y * qa.y + ka.z * qa.z + ka.w * qa.w;
            p = dpp_add<0xB1>(p);
            p = dpp_add<0x4E>(p);
            p = dpp_add<0x141>(p);
            p = dpp_add<0x140>(p);
            if (j == 0) sc4[cb][t][2] = p;
        }
        __syncthreads();
        if (c + 1 < T_ / CH) stage((c + 1) * CH, (c + 1) & 1);

        #pragma unroll 4
        for (int t = 0; t < CH; t++) {
            float2v kf = *(const float2v*)&qk[cb][t][64 + kl * 2];
            float2v qf = *(const float2v*)&qk[cb][t][kl * 2];
            float4 sv = *(const float4*)&sc4[cb][t][0];   // beta, tg, kq (broadcast)
            float2 vgv = vg[cb][t][vl];                   // {v, gate} (broadcast)

            const float decay = sv.y * rho_hr;
            float2v t1 = cw * sr - sw * si;
            float2v u1 = sw * sr + cw * si;
            float2v d2; d2.x = decay; d2.y = decay;
            float2v rr = d2 * t1;
            si = d2 * u1;

            float2v pk2 = rr * kf;
            float2v pq2 = rr * qf;
            float2v pp; pp.x = pk2.x + pk2.y; pp.y = pq2.x + pq2.y;
            pp = dpp_add2<0xB1>(pp);     // xor1
            pp = dpp_add2<0x4E>(pp);     // xor2
            pp = dpp_add2<0x141>(pp);    // quads within 8 (half-mirror)
            pp = dpp_add2<0x140>(pp);    // halves within 16 (mirror)
            pp = swz16_add2(pp);         // xor16 across 32-lane group

            const float sc = sv.x * (vgv.x - pp.x);
            float2v sc2; sc2.x = sc; sc2.y = sc;
            sr = rr + sc2 * kf;
            const float rp = pp.y + sc * sv.z;   // = sum(sr_new * q)
            if (kl == 0) atomicAdd(dst + (size_t)(c * CH + t) * 512, mw * rp * vgv.y);
        }
        __syncthreads();
    }
}

// ---------------- Kernel 4: output GEMM, A = fp32 Acomb converted inline ---------------
__global__ __launch_bounds__(256, 2) void out_mfma(const float* __restrict__ Af,
        const ushort* __restrict__ BTb, float* __restrict__ C)
{
    __shared__ ushort sA[2][64][40];
    __shared__ ushort sB[2][64][40];
    const int n0 = blockIdx.x * 64, m0 = blockIdx.y * 64;
    const int tid = threadIdx.x;
    const int lane = tid & 63, w = tid >> 6;
    const int wm = w & 1, wn = w >> 1;
    const int l16 = lane & 15, quad = lane >> 4;
    const int srow = tid >> 2, skq = (tid & 3) * 8;
    const float* Ag = Af + (size_t)(m0 + srow) * 512 + skq;
    const ushort* Bg = BTb + (size_t)(n0 + srow) * 512 + skq;
    float4 fa0 = *(const float4*)Ag;
    float4 fa1 = *(const float4*)(Ag + 4);
    short8 rb = *(const short8*)Bg;
    float4v acc00 = {0,0,0,0}, acc01 = {0,0,0,0}, acc10 = {0,0,0,0}, acc11 = {0,0,0,0};
    for (int kt = 0; kt < 16; kt++) {
        const int cb = kt & 1;
        short8 ra;
        ra[0]=f2bf(fa0.x); ra[1]=f2bf(fa0.y); ra[2]=f2bf(fa0.z); ra[3]=f2bf(fa0.w);
        ra[4]=f2bf(fa1.x); ra[5]=f2bf(fa1.y); ra[6]=f2bf(fa1.z); ra[7]=f2bf(fa1.w);
        *(short8*)&sA[cb][srow][skq] = ra;
        *(short8*)&sB[cb][srow][skq] = rb;
        __syncthreads();
        if (kt + 1 < 16) {
            fa0 = *(const float4*)(Ag + (kt + 1) * 32);
            fa1 = *(const float4*)(Ag + (kt + 1) * 32 + 4);
            rb = *(const short8*)(Bg + (kt + 1) * 32);
        }
        short8 a0 = *(const short8*)&sA[cb][wm * 32 + l16][quad * 8];
        short8 a1 = *(const short8*)&sA[cb][wm * 32 + 16 + l16][quad * 8];
        short8 b0 = *(const short8*)&sB[cb][wn * 32 + l16][quad * 8];
        short8 b1 = *(const short8*)&sB[cb][wn * 32 + 16 + l16][quad * 8];
        acc00 = __builtin_amdgcn_mfma_f32_16x16x32_bf16(a0, b0, acc00, 0, 0, 0);
        acc01 = __builtin_amdgcn_mfma_f32_16x16x32_bf16(a0, b1, acc01, 0, 0, 0);
        acc10 = __builtin_amdgcn_mfma_f32_16x16x32_bf16(a1, b0, acc10, 0, 0, 0);
        acc11 = __builtin_amdgcn_mfma_f32_16x16x32_bf16(a1, b1, acc11, 0, 0, 0);
    }
    const int colb = n0 + wn * 32 + l16;
    const int rowb = m0 + wm * 32 + quad * 4;
    #pragma unroll
    for (int r2 = 0; r2 < 4; r2++) {
        C[(size_t)(rowb + r2) * 1024 + colb] = acc00[r2];
        C[(size_t)(rowb + r2) * 1024 + colb + 16] = acc01[r2];
        C[(size_t)(rowb + 16 + r2) * 1024 + colb] = acc10[r2];
        C[(size_t)(rowb + 16 + r2) * 1024 + colb + 16] = acc11[r2];
    }
}

extern "C" void kernel_launch(void* const* d_in, const int* in_sizes, int n_in,
                              void* d_out, int out_size, void* d_ws, size_t ws_size,
                              hipStream_t stream) {
    const float* x   = (const float*)d_in[0];
    const float* Wq  = (const float*)d_in[1];
    const float* Wk  = (const float*)d_in[2];
    const float* Wv  = (const float*)d_in[3];
    const float* Wb  = (const float*)d_in[4];
    const float* Wtg = (const float*)d_in[5];
    const float* ml  = (const float*)d_in[6];
    const float* ldc = (const float*)d_in[7];
    const float* ols = (const float*)d_in[8];
    const float* Wg  = (const float*)d_in[9];
    const float* Wo  = (const float*)d_in[10];
    float* out = (float*)d_out;

    float* ws = (float*)d_ws;
    float* proj    = ws;                                 // 557056 f
    float* cosw    = proj + 256 * NPROJ;                 // 4096
    float* sinw    = cosw + 4096;                        // 4096
    float* rho     = sinw + 4096;                        // 64
    float* modew   = rho + 64;                           // 64
    ushort* xb     = (ushort*)(modew + 64);              // 262144 us = 131072 f
    ushort* wotb   = (ushort*)((float*)xb + 131072);     // 524288 us = 262144 f
    float*  Acomb  = (float*)wotb + 262144;              // 131072 f
    ushort* wtb    = (ushort*)(Acomb + 131072);          // 2228224 us = 1114112 f

    prep_kernel<<<784, 256, 0, stream>>>(x, Wq, Wk, Wv, Wb, Wtg, Wg, Wo,
                                         ml, ldc, ols, cosw, sinw, rho, modew,
                                         xb, wtb, wotb, Acomb);
    proj_mfma<<<dim3(34, 4), 256, 0, stream>>>(xb, wtb, proj);
    scan_kernel<<<512, 512, 0, stream>>>(proj, cosw, sinw, rho, modew, Acomb);
    out_mfma<<<dim3(16, 4), 256, 0, stream>>>(Acomb, wotb, out);
}

// Round 8
// 139.382 us; speedup vs baseline: 2.3866x; 1.0847x over previous
//
#include <hip/hip_runtime.h>
#include <math.h>

#define T_ 128
#define NPROJ 2176  // cols: [0,512)=Q [512,1024)=K [1024,1536)=V [1536,1600)=beta [1600,1664)=tg [1664,2176)=gate
#define CH 32       // scan chunk

typedef __attribute__((ext_vector_type(8))) short short8;
typedef __attribute__((ext_vector_type(4))) float float4v;
typedef __attribute__((ext_vector_type(2))) float float2v;

__device__ __forceinline__ ushort f2bf(float x) {
    unsigned u = __float_as_uint(x);
    u += 0x7FFF + ((u >> 16) & 1);   // RNE
    return (ushort)(u >> 16);
}

// fused DPP butterfly add: compiles to a single v_add_f32_dpp
template<int CTRL>
__device__ __forceinline__ float dpp_add(float x) {
    int xi = __float_as_int(x);
    int yi = __builtin_amdgcn_update_dpp(xi, xi, CTRL, 0xF, 0xF, false);
    return x + __int_as_float(yi);
}

// ---------------- Kernel 1: prep = params + x->bf16 + W/Wo transpose + Acomb zero -----
__global__ __launch_bounds__(256) void prep_kernel(
    const float* __restrict__ x,
    const float* __restrict__ Wq, const float* __restrict__ Wk,
    const float* __restrict__ Wv, const float* __restrict__ Wb,
    const float* __restrict__ Wtg, const float* __restrict__ Wg,
    const float* __restrict__ Wo,
    const float* __restrict__ mode_logits, const float* __restrict__ log_decay,
    const float* __restrict__ ols,
    float* __restrict__ cosw, float* __restrict__ sinw,
    float* __restrict__ rho, float* __restrict__ modew,
    ushort* __restrict__ xb, ushort* __restrict__ wtb, ushort* __restrict__ wotb,
    float* __restrict__ Acomb)
{
    __shared__ ushort tile[64][68];
    const int blk = blockIdx.x, tid = threadIdx.x;
    if (blk < 16) {
        int idx = blk * 256 + tid;
        if (idx >= 64 * 64) return;
        int t = idx >> 6;   // hr
        int k = idx & 63;
        int h = t >> 3;
        if (k == 0) {
            float ld = log_decay[t];
            rho[t] = 1.0f / (1.0f + expf(ld));  // exp(-softplus) == sigmoid(-x)
            float m = -1e30f;
            for (int i = 0; i < 8; i++) m = fmaxf(m, mode_logits[h * 8 + i]);
            float sum = 0.0f;
            for (int i = 0; i < 8; i++) sum += expf(mode_logits[h * 8 + i] - m);
            modew[t] = expf(mode_logits[t] - m) / sum;
        }
        float osc = expf(ols[t]);
        int p = k >> 1;
        float invf = expf(-((float)(2 * p) / 64.0f) * logf(10000.0f));
        float w = osc * invf;
        cosw[idx] = cosf(w);
        sinw[idx] = sinf(w);
        return;
    }
    if (blk < 80) {   // x convert
        int base = (blk - 16) * 4096 + tid * 16;
        float4 f0 = *(const float4*)&x[base];
        float4 f1 = *(const float4*)&x[base + 4];
        float4 f2 = *(const float4*)&x[base + 8];
        float4 f3 = *(const float4*)&x[base + 12];
        short8 o0, o1;
        o0[0]=f2bf(f0.x); o0[1]=f2bf(f0.y); o0[2]=f2bf(f0.z); o0[3]=f2bf(f0.w);
        o0[4]=f2bf(f1.x); o0[5]=f2bf(f1.y); o0[6]=f2bf(f1.z); o0[7]=f2bf(f1.w);
        o1[0]=f2bf(f2.x); o1[1]=f2bf(f2.y); o1[2]=f2bf(f2.z); o1[3]=f2bf(f2.w);
        o1[4]=f2bf(f3.x); o1[5]=f2bf(f3.y); o1[6]=f2bf(f3.z); o1[7]=f2bf(f3.w);
        *(short8*)&xb[base] = o0;
        *(short8*)&xb[base + 8] = o1;
        return;
    }
    if (blk >= 752) {  // zero Acomb
        int base = (blk - 752) * 4096 + tid * 16;
        float4 z = make_float4(0.f, 0.f, 0.f, 0.f);
        *(float4*)&Acomb[base] = z;
        *(float4*)&Acomb[base + 4] = z;
        *(float4*)&Acomb[base + 8] = z;
        *(float4*)&Acomb[base + 12] = z;
        return;
    }
    // transpose-convert
    const float* src; int ld, c0, n0, k0, ldd; ushort* dst;
    if (blk < 624) {
        int b3 = blk - 80; int nt = b3 >> 4, kt = b3 & 15;
        n0 = nt * 64; k0 = kt * 64;
        if (n0 < 512)       { src = Wq;  c0 = n0;        ld = 512; }
        else if (n0 < 1024) { src = Wk;  c0 = n0 - 512;  ld = 512; }
        else if (n0 < 1536) { src = Wv;  c0 = n0 - 1024; ld = 512; }
        else if (n0 < 1600) { src = Wb;  c0 = n0 - 1536; ld = 64;  }
        else if (n0 < 1664) { src = Wtg; c0 = n0 - 1600; ld = 64;  }
        else                { src = Wg;  c0 = n0 - 1664; ld = 512; }
        dst = wtb; ldd = 1024;
    } else {
        int b4 = blk - 624; int nt = b4 >> 3, kt = b4 & 7;
        n0 = nt * 64; k0 = kt * 64;
        src = Wo; c0 = n0; ld = 1024; dst = wotb; ldd = 512;
    }
    #pragma unroll
    for (int rep = 0; rep < 4; rep++) {
        int k = rep * 16 + (tid >> 4);
        int nc = (tid & 15) * 4;
        float4 f = *(const float4*)&src[(size_t)(k0 + k) * ld + c0 + nc];
        tile[nc + 0][k] = f2bf(f.x);
        tile[nc + 1][k] = f2bf(f.y);
        tile[nc + 2][k] = f2bf(f.z);
        tile[nc + 3][k] = f2bf(f.w);
    }
    __syncthreads();
    #pragma unroll
    for (int rep = 0; rep < 4; rep++) {
        int n = rep * 16 + (tid >> 4);
        int kc = (tid & 15) * 4;
        uint2 uu = *(const uint2*)&tile[n][kc];
        *(uint2*)&dst[(size_t)(n0 + n) * ldd + k0 + kc] = uu;
    }
}

// ---------------- Kernel 2: proj MFMA GEMM ---------------------------------------------
__global__ __launch_bounds__(256, 2) void proj_mfma(const ushort* __restrict__ Ab,
        const ushort* __restrict__ BTb, float* __restrict__ proj)
{
    __shared__ ushort sA[2][64][40];
    __shared__ ushort sB[2][64][40];
    const int n0 = blockIdx.x * 64, m0 = blockIdx.y * 64;
    const int tid = threadIdx.x;
    const int lane = tid & 63, w = tid >> 6;
    const int wm = w & 1, wn = w >> 1;
    const int l16 = lane & 15, quad = lane >> 4;
    const int srow = tid >> 2, skq = (tid & 3) * 8;
    const ushort* Ag = Ab + (size_t)(m0 + srow) * 1024 + skq;
    const ushort* Bg = BTb + (size_t)(n0 + srow) * 1024 + skq;
    short8 ra = *(const short8*)Ag;
    short8 rb = *(const short8*)Bg;
    float4v acc00 = {0,0,0,0}, acc01 = {0,0,0,0}, acc10 = {0,0,0,0}, acc11 = {0,0,0,0};
    for (int kt = 0; kt < 32; kt++) {
        const int cb = kt & 1;
        *(short8*)&sA[cb][srow][skq] = ra;
        *(short8*)&sB[cb][srow][skq] = rb;
        __syncthreads();
        if (kt + 1 < 32) {
            ra = *(const short8*)(Ag + (kt + 1) * 32);
            rb = *(const short8*)(Bg + (kt + 1) * 32);
        }
        short8 a0 = *(const short8*)&sA[cb][wm * 32 + l16][quad * 8];
        short8 a1 = *(const short8*)&sA[cb][wm * 32 + 16 + l16][quad * 8];
        short8 b0 = *(const short8*)&sB[cb][wn * 32 + l16][quad * 8];
        short8 b1 = *(const short8*)&sB[cb][wn * 32 + 16 + l16][quad * 8];
        acc00 = __builtin_amdgcn_mfma_f32_16x16x32_bf16(a0, b0, acc00, 0, 0, 0);
        acc01 = __builtin_amdgcn_mfma_f32_16x16x32_bf16(a0, b1, acc01, 0, 0, 0);
        acc10 = __builtin_amdgcn_mfma_f32_16x16x32_bf16(a1, b0, acc10, 0, 0, 0);
        acc11 = __builtin_amdgcn_mfma_f32_16x16x32_bf16(a1, b1, acc11, 0, 0, 0);
    }
    const bool sig = (n0 >= 1536);
    const int colb = n0 + wn * 32 + l16;
    const int rowb = m0 + wm * 32 + quad * 4;
    #pragma unroll
    for (int r2 = 0; r2 < 4; r2++) {
        float v00 = acc00[r2], v01 = acc01[r2], v10 = acc10[r2], v11 = acc11[r2];
        if (sig) {
            v00 = 1.0f / (1.0f + expf(-v00));
            v01 = 1.0f / (1.0f + expf(-v01));
            v10 = 1.0f / (1.0f + expf(-v10));
            v11 = 1.0f / (1.0f + expf(-v11));
        }
        proj[(size_t)(rowb + r2) * NPROJ + colb] = v00;
        proj[(size_t)(rowb + r2) * NPROJ + colb + 16] = v01;
        proj[(size_t)(rowb + 16 + r2) * NPROJ + colb] = v10;
        proj[(size_t)(rowb + 16 + r2) * NPROJ + colb + 16] = v11;
    }
}

// ---------------- Kernel 3: scan — R5 shape, fully-unrolled steps, imm LDS offsets -----
// grid 512 = b(2) x hr(64) x s(4); block 256: vl = tid>>4 (16 v), kl = tid&15 (4 k each)
__global__ __launch_bounds__(256, 2) void scan_kernel(const float* __restrict__ proj,
        const float* __restrict__ cosw, const float* __restrict__ sinw,
        const float* __restrict__ rho, const float* __restrict__ modew,
        float* __restrict__ Acomb)
{
    __shared__ float qk[2][CH][128];     // per t: [0..63]=q, [64..127]=k   (32 KB)
    __shared__ float2 vg[2][CH][16];     // {v, gate} per (t, vl)           (8 KB)
    __shared__ float sc4[2][CH][4];      // [0]=beta [1]=tg [2]=kq          (1 KB)
    __shared__ float obuf[CH][16];       // per-chunk outputs               (2 KB)

    const int bi = blockIdx.x;
    const int s  = bi & 3;
    const int hr = (bi >> 2) & 63;
    const int b  = bi >> 8;
    const int h = hr >> 3, r = hr & 7;
    const int tid = threadIdx.x;
    const int vl = tid >> 4;             // 0..15
    const int kl = tid & 15;             // 0..15, low 4 lane bits

    float2v cw0, cw1, sw0, sw1;
    cw0.x = cosw[hr * 64 + kl * 4 + 0]; cw0.y = cosw[hr * 64 + kl * 4 + 1];
    cw1.x = cosw[hr * 64 + kl * 4 + 2]; cw1.y = cosw[hr * 64 + kl * 4 + 3];
    sw0.x = sinw[hr * 64 + kl * 4 + 0]; sw0.y = sinw[hr * 64 + kl * 4 + 1];
    sw1.x = sinw[hr * 64 + kl * 4 + 2]; sw1.y = sinw[hr * 64 + kl * 4 + 3];
    const float rho_hr = rho[hr];
    const float mw = modew[hr];
    float2v sr0 = {0,0}, sr1 = {0,0}, si0 = {0,0}, si1 = {0,0};

    const float* pb = proj + (size_t)b * T_ * NPROJ;
    const int qbase = h * 64;
    const int kbase = 512 + h * 64;
    const int vbase = 1024 + h * 64 + s * 16;
    const int gbase = 1664 + h * 64 + s * 16;
    const int boff  = 1536 + h * 8 + r;
    const int goff  = 1600 + h * 8 + r;

    auto stage = [&](int t0, int nb) {
        #pragma unroll
        for (int rep = 0; rep < 4; rep++) {
            int idx = rep * 256 + tid;
            int t = idx >> 5, sub = idx & 31;
            const float* row = pb + (size_t)(t0 + t) * NPROJ;
            float4 val = *(const float4*)(row + (sub < 16 ? qbase + sub * 4
                                                          : kbase + (sub - 16) * 4));
            *(float4*)&qk[nb][t][sub * 4] = val;
        }
        #pragma unroll
        for (int rep = 0; rep < 2; rep++) {
            int idx = rep * 256 + tid;
            int t = idx >> 4, v2 = idx & 15;
            const float* row = pb + (size_t)(t0 + t) * NPROJ;
            vg[nb][t][v2] = make_float2(row[vbase + v2], row[gbase + v2]);
        }
        if (tid < CH)            sc4[nb][tid][0]      = pb[(size_t)(t0 + tid) * NPROJ + boff];
        else if (tid < 2 * CH)   sc4[nb][tid - CH][1] = pb[(size_t)(t0 + tid - CH) * NPROJ + goff];
    };

    stage(0, 0);
    __syncthreads();

    float* dstb = Acomb + ((size_t)b * 128) * 512 + h * 64 + s * 16;

    for (int c = 0; c < T_ / CH; c++) {
        const int cb = c & 1;
        {   // hoisted kq_t for this chunk: t = tid>>3 (0..31), j = tid&7, 8 elems each
            int t = tid >> 3, j = tid & 7;
            float4 ka = *(const float4*)&qk[cb][t][64 + j * 8];
            float4 kb4 = *(const float4*)&qk[cb][t][64 + j * 8 + 4];
            float4 qa = *(const float4*)&qk[cb][t][j * 8];
            float4 qb4 = *(const float4*)&qk[cb][t][j * 8 + 4];
            float p = ka.x * qa.x + ka.y * qa.y + ka.z * qa.z + ka.w * qa.w
                    + kb4.x * qb4.x + kb4.y * qb4.y + kb4.z * qb4.z + kb4.w * qb4.w;
            p = dpp_add<0xB1>(p);   // xor1
            p = dpp_add<0x4E>(p);   // xor2
            p = dpp_add<0x141>(p);  // xor4 (half-mirror within 8)
            if (j == 0) sc4[cb][t][2] = p;
        }
        // flush previous chunk's outputs (obuf written before last barrier)
        if (c > 0) {
            #pragma unroll
            for (int rep = 0; rep < 2; rep++) {
                int idx = rep * 256 + tid;
                int t = idx >> 4, v2 = idx & 15;
                atomicAdd(dstb + (size_t)((c - 1) * CH + t) * 512 + v2, obuf[t][v2]);
            }
        }
        __syncthreads();
        if (c + 1 < T_ / CH) stage((c + 1) * CH, (c + 1) & 1);

        // fully unrolled steps: all LDS reads at immediate offsets off per-chunk bases
        const float* qkb = &qk[cb][0][0];
        const float2* vgb = &vg[cb][0][0];
        const float4* svb = (const float4*)&sc4[cb][0][0];
        #pragma unroll
        for (int t = 0; t < CH; t++) {
            float4 kf = *(const float4*)(qkb + t * 128 + 64 + kl * 4);
            float4 qf = *(const float4*)(qkb + t * 128 + kl * 4);
            float4 sv = svb[t];                 // beta, tg, kq (broadcast)
            float2 vgv = vgb[t * 16 + vl];      // {v, gate} (broadcast x16)

            const float decay = sv.y * rho_hr;
            float2v k0; k0.x = kf.x; k0.y = kf.y;
            float2v k1; k1.x = kf.z; k1.y = kf.w;
            float2v q0; q0.x = qf.x; q0.y = qf.y;
            float2v q1; q1.x = qf.z; q1.y = qf.w;

            float2v t1 = cw0 * sr0 - sw0 * si0;
            float2v u1 = sw0 * sr0 + cw0 * si0;
            float2v t2 = cw1 * sr1 - sw1 * si1;
            float2v u2 = sw1 * sr1 + cw1 * si1;
            float2v d2; d2.x = decay; d2.y = decay;
            float2v rr0 = d2 * t1, rr1 = d2 * t2;
            si0 = d2 * u1; si1 = d2 * u2;

            float2v pk2 = rr0 * k0 + rr1 * k1;
            float2v pq2 = rr0 * q0 + rr1 * q1;
            float pk = pk2.x + pk2.y;
            float pq = pq2.x + pq2.y;
            pk = dpp_add<0xB1>(pk);  pq = dpp_add<0xB1>(pq);   // xor1
            pk = dpp_add<0x4E>(pk);  pq = dpp_add<0x4E>(pq);   // xor2
            pk = dpp_add<0x141>(pk); pq = dpp_add<0x141>(pq);  // xor4
            pk = dpp_add<0x140>(pk); pq = dpp_add<0x140>(pq);  // xor8 (mirror in 16)

            const float sc = sv.x * (vgv.x - pk);
            float2v sc2; sc2.x = sc; sc2.y = sc;
            sr0 = rr0 + sc2 * k0;
            sr1 = rr1 + sc2 * k1;
            const float rp = pq + sc * sv.z;    // = sum(sr_new * q)
            if (kl == 0) obuf[t][vl] = mw * rp * vgv.y;
        }
        __syncthreads();
    }
    // final flush
    #pragma unroll
    for (int rep = 0; rep < 2; rep++) {
        int idx = rep * 256 + tid;
        int t = idx >> 4, v2 = idx & 15;
        atomicAdd(dstb + (size_t)(3 * CH + t) * 512 + v2, obuf[t][v2]);
    }
}

// ---------------- Kernel 4: output GEMM, A = fp32 Acomb converted inline ---------------
__global__ __launch_bounds__(256, 2) void out_mfma(const float* __restrict__ Af,
        const ushort* __restrict__ BTb, float* __restrict__ C)
{
    __shared__ ushort sA[2][64][40];
    __shared__ ushort sB[2][64][40];
    const int n0 = blockIdx.x * 64, m0 = blockIdx.y * 64;
    const int tid = threadIdx.x;
    const int lane = tid & 63, w = tid >> 6;
    const int wm = w & 1, wn = w >> 1;
    const int l16 = lane & 15, quad = lane >> 4;
    const int srow = tid >> 2, skq = (tid & 3) * 8;
    const float* Ag = Af + (size_t)(m0 + srow) * 512 + skq;
    const ushort* Bg = BTb + (size_t)(n0 + srow) * 512 + skq;
    float4 fa0 = *(const float4*)Ag;
    float4 fa1 = *(const float4*)(Ag + 4);
    short8 rb = *(const short8*)Bg;
    float4v acc00 = {0,0,0,0}, acc01 = {0,0,0,0}, acc10 = {0,0,0,0}, acc11 = {0,0,0,0};
    for (int kt = 0; kt < 16; kt++) {
        const int cb = kt & 1;
        short8 ra;
        ra[0]=f2bf(fa0.x); ra[1]=f2bf(fa0.y); ra[2]=f2bf(fa0.z); ra[3]=f2bf(fa0.w);
        ra[4]=f2bf(fa1.x); ra[5]=f2bf(fa1.y); ra[6]=f2bf(fa1.z); ra[7]=f2bf(fa1.w);
        *(short8*)&sA[cb][srow][skq] = ra;
        *(short8*)&sB[cb][srow][skq] = rb;
        __syncthreads();
        if (kt + 1 < 16) {
            fa0 = *(const float4*)(Ag + (kt + 1) * 32);
            fa1 = *(const float4*)(Ag + (kt + 1) * 32 + 4);
            rb = *(const short8*)(Bg + (kt + 1) * 32);
        }
        short8 a0 = *(const short8*)&sA[cb][wm * 32 + l16][quad * 8];
        short8 a1 = *(const short8*)&sA[cb][wm * 32 + 16 + l16][quad * 8];
        short8 b0 = *(const short8*)&sB[cb][wn * 32 + l16][quad * 8];
        short8 b1 = *(const short8*)&sB[cb][wn * 32 + 16 + l16][quad * 8];
        acc00 = __builtin_amdgcn_mfma_f32_16x16x32_bf16(a0, b0, acc00, 0, 0, 0);
        acc01 = __builtin_amdgcn_mfma_f32_16x16x32_bf16(a0, b1, acc01, 0, 0, 0);
        acc10 = __builtin_amdgcn_mfma_f32_16x16x32_bf16(a1, b0, acc10, 0, 0, 0);
        acc11 = __builtin_amdgcn_mfma_f32_16x16x32_bf16(a1, b1, acc11, 0, 0, 0);
    }
    const int colb = n0 + wn * 32 + l16;
    const int rowb = m0 + wm * 32 + quad * 4;
    #pragma unroll
    for (int r2 = 0; r2 < 4; r2++) {
        C[(size_t)(rowb + r2) * 1024 + colb] = acc00[r2];
        C[(size_t)(rowb + r2) * 1024 + colb + 16] = acc01[r2];
        C[(size_t)(rowb + 16 + r2) * 1024 + colb] = acc10[r2];
        C[(size_t)(rowb + 16 + r2) * 1024 + colb + 16] = acc11[r2];
    }
}

extern "C" void kernel_launch(void* const* d_in, const int* in_sizes, int n_in,
                              void* d_out, int out_size, void* d_ws, size_t ws_size,
                              hipStream_t stream) {
    const float* x   = (const float*)d_in[0];
    const float* Wq  = (const float*)d_in[1];
    const float* Wk  = (const float*)d_in[2];
    const float* Wv  = (const float*)d_in[3];
    const float* Wb  = (const float*)d_in[4];
    const float* Wtg = (const float*)d_in[5];
    const float* ml  = (const float*)d_in[6];
    const float* ldc = (const float*)d_in[7];
    const float* ols = (const float*)d_in[8];
    const float* Wg  = (const float*)d_in[9];
    const float* Wo  = (const float*)d_in[10];
    float* out = (float*)d_out;

    float* ws = (float*)d_ws;
    float* proj    = ws;                                 // 557056 f
    float* cosw    = proj + 256 * NPROJ;                 // 4096
    float* sinw    = cosw + 4096;                        // 4096
    float* rho     = sinw + 4096;                        // 64
    float* modew   = rho + 64;                           // 64
    ushort* xb     = (ushort*)(modew + 64);              // 262144 us = 131072 f
    ushort* wotb   = (ushort*)((float*)xb + 131072);     // 524288 us = 262144 f
    float*  Acomb  = (float*)wotb + 262144;              // 131072 f
    ushort* wtb    = (ushort*)(Acomb + 131072);          // 2228224 us = 1114112 f

    prep_kernel<<<784, 256, 0, stream>>>(x, Wq, Wk, Wv, Wb, Wtg, Wg, Wo,
                                         ml, ldc, ols, cosw, sinw, rho, modew,
                                         xb, wtb, wotb, Acomb);
    proj_mfma<<<dim3(34, 4), 256, 0, stream>>>(xb, wtb, proj);
    scan_kernel<<<512, 256, 0, stream>>>(proj, cosw, sinw, rho, modew, Acomb);
    out_mfma<<<dim3(16, 4), 256, 0, stream>>>(Acomb, wotb, out);
}

// Round 9
// 137.495 us; speedup vs baseline: 2.4193x; 1.0137x over previous
//
#include <hip/hip_runtime.h>
#include <math.h>

#define T_ 128
#define NPROJ 2176  // cols: [0,512)=Q [512,1024)=K [1024,1536)=V [1536,1600)=beta [1600,1664)=tg [1664,2176)=gate
#define CH 32       // scan chunk

typedef __attribute__((ext_vector_type(8))) short short8;
typedef __attribute__((ext_vector_type(4))) float float4v;
typedef __attribute__((ext_vector_type(2))) float float2v;

__device__ __forceinline__ ushort f2bf(float x) {
    unsigned u = __float_as_uint(x);
    u += 0x7FFF + ((u >> 16) & 1);   // RNE
    return (ushort)(u >> 16);
}

// fused DPP butterfly add: compiles to a single v_add_f32_dpp
template<int CTRL>
__device__ __forceinline__ float dpp_add(float x) {
    int xi = __float_as_int(x);
    int yi = __builtin_amdgcn_update_dpp(xi, xi, CTRL, 0xF, 0xF, false);
    return x + __int_as_float(yi);
}

// ---------------- Kernel 1: prep = params + x->bf16 + W/Wo transpose + Acomb zero -----
__global__ __launch_bounds__(256) void prep_kernel(
    const float* __restrict__ x,
    const float* __restrict__ Wq, const float* __restrict__ Wk,
    const float* __restrict__ Wv, const float* __restrict__ Wb,
    const float* __restrict__ Wtg, const float* __restrict__ Wg,
    const float* __restrict__ Wo,
    const float* __restrict__ mode_logits, const float* __restrict__ log_decay,
    const float* __restrict__ ols,
    float* __restrict__ cosw, float* __restrict__ sinw,
    float* __restrict__ rho, float* __restrict__ modew,
    ushort* __restrict__ xb, ushort* __restrict__ wtb, ushort* __restrict__ wotb,
    float* __restrict__ Acomb)
{
    __shared__ ushort tile[64][68];
    const int blk = blockIdx.x, tid = threadIdx.x;
    if (blk < 16) {
        int idx = blk * 256 + tid;
        if (idx >= 64 * 64) return;
        int t = idx >> 6;   // hr
        int k = idx & 63;
        int h = t >> 3;
        if (k == 0) {
            float ld = log_decay[t];
            rho[t] = 1.0f / (1.0f + expf(ld));  // exp(-softplus) == sigmoid(-x)
            float m = -1e30f;
            for (int i = 0; i < 8; i++) m = fmaxf(m, mode_logits[h * 8 + i]);
            float sum = 0.0f;
            for (int i = 0; i < 8; i++) sum += expf(mode_logits[h * 8 + i] - m);
            modew[t] = expf(mode_logits[t] - m) / sum;
        }
        float osc = expf(ols[t]);
        int p = k >> 1;
        float invf = expf(-((float)(2 * p) / 64.0f) * logf(10000.0f));
        float w = osc * invf;
        cosw[idx] = cosf(w);
        sinw[idx] = sinf(w);
        return;
    }
    if (blk < 80) {   // x convert
        int base = (blk - 16) * 4096 + tid * 16;
        float4 f0 = *(const float4*)&x[base];
        float4 f1 = *(const float4*)&x[base + 4];
        float4 f2 = *(const float4*)&x[base + 8];
        float4 f3 = *(const float4*)&x[base + 12];
        short8 o0, o1;
        o0[0]=f2bf(f0.x); o0[1]=f2bf(f0.y); o0[2]=f2bf(f0.z); o0[3]=f2bf(f0.w);
        o0[4]=f2bf(f1.x); o0[5]=f2bf(f1.y); o0[6]=f2bf(f1.z); o0[7]=f2bf(f1.w);
        o1[0]=f2bf(f2.x); o1[1]=f2bf(f2.y); o1[2]=f2bf(f2.z); o1[3]=f2bf(f2.w);
        o1[4]=f2bf(f3.x); o1[5]=f2bf(f3.y); o1[6]=f2bf(f3.z); o1[7]=f2bf(f3.w);
        *(short8*)&xb[base] = o0;
        *(short8*)&xb[base + 8] = o1;
        return;
    }
    if (blk >= 752) {  // zero Acomb
        int base = (blk - 752) * 4096 + tid * 16;
        float4 z = make_float4(0.f, 0.f, 0.f, 0.f);
        *(float4*)&Acomb[base] = z;
        *(float4*)&Acomb[base + 4] = z;
        *(float4*)&Acomb[base + 8] = z;
        *(float4*)&Acomb[base + 12] = z;
        return;
    }
    // transpose-convert
    const float* src; int ld, c0, n0, k0, ldd; ushort* dst;
    if (blk < 624) {
        int b3 = blk - 80; int nt = b3 >> 4, kt = b3 & 15;
        n0 = nt * 64; k0 = kt * 64;
        if (n0 < 512)       { src = Wq;  c0 = n0;        ld = 512; }
        else if (n0 < 1024) { src = Wk;  c0 = n0 - 512;  ld = 512; }
        else if (n0 < 1536) { src = Wv;  c0 = n0 - 1024; ld = 512; }
        else if (n0 < 1600) { src = Wb;  c0 = n0 - 1536; ld = 64;  }
        else if (n0 < 1664) { src = Wtg; c0 = n0 - 1600; ld = 64;  }
        else                { src = Wg;  c0 = n0 - 1664; ld = 512; }
        dst = wtb; ldd = 1024;
    } else {
        int b4 = blk - 624; int nt = b4 >> 3, kt = b4 & 7;
        n0 = nt * 64; k0 = kt * 64;
        src = Wo; c0 = n0; ld = 1024; dst = wotb; ldd = 512;
    }
    #pragma unroll
    for (int rep = 0; rep < 4; rep++) {
        int k = rep * 16 + (tid >> 4);
        int nc = (tid & 15) * 4;
        float4 f = *(const float4*)&src[(size_t)(k0 + k) * ld + c0 + nc];
        tile[nc + 0][k] = f2bf(f.x);
        tile[nc + 1][k] = f2bf(f.y);
        tile[nc + 2][k] = f2bf(f.z);
        tile[nc + 3][k] = f2bf(f.w);
    }
    __syncthreads();
    #pragma unroll
    for (int rep = 0; rep < 4; rep++) {
        int n = rep * 16 + (tid >> 4);
        int kc = (tid & 15) * 4;
        uint2 uu = *(const uint2*)&tile[n][kc];
        *(uint2*)&dst[(size_t)(n0 + n) * ldd + k0 + kc] = uu;
    }
}

// ---------------- Kernel 2: proj MFMA GEMM ---------------------------------------------
__global__ __launch_bounds__(256, 2) void proj_mfma(const ushort* __restrict__ Ab,
        const ushort* __restrict__ BTb, float* __restrict__ proj)
{
    __shared__ ushort sA[2][64][40];
    __shared__ ushort sB[2][64][40];
    const int n0 = blockIdx.x * 64, m0 = blockIdx.y * 64;
    const int tid = threadIdx.x;
    const int lane = tid & 63, w = tid >> 6;
    const int wm = w & 1, wn = w >> 1;
    const int l16 = lane & 15, quad = lane >> 4;
    const int srow = tid >> 2, skq = (tid & 3) * 8;
    const ushort* Ag = Ab + (size_t)(m0 + srow) * 1024 + skq;
    const ushort* Bg = BTb + (size_t)(n0 + srow) * 1024 + skq;
    short8 ra = *(const short8*)Ag;
    short8 rb = *(const short8*)Bg;
    float4v acc00 = {0,0,0,0}, acc01 = {0,0,0,0}, acc10 = {0,0,0,0}, acc11 = {0,0,0,0};
    for (int kt = 0; kt < 32; kt++) {
        const int cb = kt & 1;
        *(short8*)&sA[cb][srow][skq] = ra;
        *(short8*)&sB[cb][srow][skq] = rb;
        __syncthreads();
        if (kt + 1 < 32) {
            ra = *(const short8*)(Ag + (kt + 1) * 32);
            rb = *(const short8*)(Bg + (kt + 1) * 32);
        }
        short8 a0 = *(const short8*)&sA[cb][wm * 32 + l16][quad * 8];
        short8 a1 = *(const short8*)&sA[cb][wm * 32 + 16 + l16][quad * 8];
        short8 b0 = *(const short8*)&sB[cb][wn * 32 + l16][quad * 8];
        short8 b1 = *(const short8*)&sB[cb][wn * 32 + 16 + l16][quad * 8];
        acc00 = __builtin_amdgcn_mfma_f32_16x16x32_bf16(a0, b0, acc00, 0, 0, 0);
        acc01 = __builtin_amdgcn_mfma_f32_16x16x32_bf16(a0, b1, acc01, 0, 0, 0);
        acc10 = __builtin_amdgcn_mfma_f32_16x16x32_bf16(a1, b0, acc10, 0, 0, 0);
        acc11 = __builtin_amdgcn_mfma_f32_16x16x32_bf16(a1, b1, acc11, 0, 0, 0);
    }
    const bool sig = (n0 >= 1536);
    const int colb = n0 + wn * 32 + l16;
    const int rowb = m0 + wm * 32 + quad * 4;
    #pragma unroll
    for (int r2 = 0; r2 < 4; r2++) {
        float v00 = acc00[r2], v01 = acc01[r2], v10 = acc10[r2], v11 = acc11[r2];
        if (sig) {
            v00 = 1.0f / (1.0f + expf(-v00));
            v01 = 1.0f / (1.0f + expf(-v01));
            v10 = 1.0f / (1.0f + expf(-v10));
            v11 = 1.0f / (1.0f + expf(-v11));
        }
        proj[(size_t)(rowb + r2) * NPROJ + colb] = v00;
        proj[(size_t)(rowb + r2) * NPROJ + colb + 16] = v01;
        proj[(size_t)(rowb + 16 + r2) * NPROJ + colb] = v10;
        proj[(size_t)(rowb + 16 + r2) * NPROJ + colb + 16] = v11;
    }
}

// ---------------- Kernel 3: scan — global prefetch->regs + explicit LDS step prefetch --
// grid 512 = b(2) x hr(64) x s(4); block 256: vl = tid>>4 (16 v), kl = tid&15 (4 k each)
__global__ __launch_bounds__(256, 2) void scan_kernel(const float* __restrict__ proj,
        const float* __restrict__ cosw, const float* __restrict__ sinw,
        const float* __restrict__ rho, const float* __restrict__ modew,
        float* __restrict__ Acomb)
{
    __shared__ float qk[2][CH][128];     // per t: [0..63]=q, [64..127]=k   (32 KB)
    __shared__ float2 vg[2][CH][16];     // {v, gate} per (t, vl)           (8 KB)
    __shared__ float sc4[2][CH][4];      // [0]=beta [1]=tg [2]=kq          (1 KB)
    __shared__ float obuf[CH][16];       // per-chunk outputs               (2 KB)

    const int bi = blockIdx.x;
    const int s  = bi & 3;
    const int hr = (bi >> 2) & 63;
    const int b  = bi >> 8;
    const int h = hr >> 3, r = hr & 7;
    const int tid = threadIdx.x;
    const int vl = tid >> 4;             // 0..15
    const int kl = tid & 15;             // 0..15, low 4 lane bits

    float2v cw0, cw1, sw0, sw1;
    cw0.x = cosw[hr * 64 + kl * 4 + 0]; cw0.y = cosw[hr * 64 + kl * 4 + 1];
    cw1.x = cosw[hr * 64 + kl * 4 + 2]; cw1.y = cosw[hr * 64 + kl * 4 + 3];
    sw0.x = sinw[hr * 64 + kl * 4 + 0]; sw0.y = sinw[hr * 64 + kl * 4 + 1];
    sw1.x = sinw[hr * 64 + kl * 4 + 2]; sw1.y = sinw[hr * 64 + kl * 4 + 3];
    const float rho_hr = rho[hr];
    const float mw = modew[hr];
    float2v sr0 = {0,0}, sr1 = {0,0}, si0 = {0,0}, si1 = {0,0};

    const float* pb = proj + (size_t)b * T_ * NPROJ;
    const int qbase = h * 64;
    const int kbase = 512 + h * 64;
    const int vbase = 1024 + h * 64 + s * 16;
    const int gbase = 1664 + h * 64 + s * 16;
    const int boff  = 1536 + h * 8 + r;
    const int goff  = 1600 + h * 8 + r;

    // stage chunk 0 directly global->LDS
    {
        #pragma unroll
        for (int rep = 0; rep < 4; rep++) {
            int idx = rep * 256 + tid;
            int t = idx >> 5, sub = idx & 31;
            const float* row = pb + (size_t)t * NPROJ;
            float4 val = *(const float4*)(row + (sub < 16 ? qbase + sub * 4
                                                          : kbase + (sub - 16) * 4));
            *(float4*)&qk[0][t][sub * 4] = val;
        }
        #pragma unroll
        for (int rep = 0; rep < 2; rep++) {
            int idx = rep * 256 + tid;
            int t = idx >> 4, v2 = idx & 15;
            const float* row = pb + (size_t)t * NPROJ;
            vg[0][t][v2] = make_float2(row[vbase + v2], row[gbase + v2]);
        }
        if (tid < CH)            sc4[0][tid][0]      = pb[(size_t)tid * NPROJ + boff];
        else if (tid < 2 * CH)   sc4[0][tid - CH][1] = pb[(size_t)(tid - CH) * NPROJ + goff];
    }
    __syncthreads();

    float* dstb = Acomb + ((size_t)b * 128) * 512 + h * 64 + s * 16;

    for (int c = 0; c < T_ / CH; c++) {
        const int cb = c & 1, nb = cb ^ 1;
        const bool have = (c + 1 < T_ / CH);

        // --- global prefetch chunk c+1 into registers (loads issued, no wait yet) ---
        float4 g_qk[4]; float2 g_vg[2]; float g_sc = 0.0f;
        if (have) {
            const int t0 = (c + 1) * CH;
            #pragma unroll
            for (int rep = 0; rep < 4; rep++) {
                int idx = rep * 256 + tid;
                int t = idx >> 5, sub = idx & 31;
                const float* row = pb + (size_t)(t0 + t) * NPROJ;
                g_qk[rep] = *(const float4*)(row + (sub < 16 ? qbase + sub * 4
                                                             : kbase + (sub - 16) * 4));
            }
            #pragma unroll
            for (int rep = 0; rep < 2; rep++) {
                int idx = rep * 256 + tid;
                int t = idx >> 4, v2 = idx & 15;
                const float* row = pb + (size_t)(t0 + t) * NPROJ;
                g_vg[rep] = make_float2(row[vbase + v2], row[gbase + v2]);
            }
            if (tid < CH)          g_sc = pb[(size_t)(t0 + tid) * NPROJ + boff];
            else if (tid < 2 * CH) g_sc = pb[(size_t)(t0 + tid - CH) * NPROJ + goff];
        }

        // --- hoisted kq_t for this chunk ---
        {
            int t = tid >> 3, j = tid & 7;
            float4 ka = *(const float4*)&qk[cb][t][64 + j * 8];
            float4 kb4 = *(const float4*)&qk[cb][t][64 + j * 8 + 4];
            float4 qa = *(const float4*)&qk[cb][t][j * 8];
            float4 qb4 = *(const float4*)&qk[cb][t][j * 8 + 4];
            float p = ka.x * qa.x + ka.y * qa.y + ka.z * qa.z + ka.w * qa.w
                    + kb4.x * qb4.x + kb4.y * qb4.y + kb4.z * qb4.z + kb4.w * qb4.w;
            p = dpp_add<0xB1>(p);   // xor1
            p = dpp_add<0x4E>(p);   // xor2
            p = dpp_add<0x141>(p);  // xor4 (half-mirror within 8)
            if (j == 0) sc4[cb][t][2] = p;
        }
        // --- flush previous chunk's outputs ---
        if (c > 0) {
            #pragma unroll
            for (int rep = 0; rep < 2; rep++) {
                int idx = rep * 256 + tid;
                int t = idx >> 4, v2 = idx & 15;
                atomicAdd(dstb + (size_t)((c - 1) * CH + t) * 512 + v2, obuf[t][v2]);
            }
        }
        __syncthreads();

        // --- 32 steps, explicit t+1 LDS prefetch ---
        const float* qkb = &qk[cb][0][0];
        const float2* vgb = &vg[cb][0][0];
        const float4* svb = (const float4*)&sc4[cb][0][0];

        float4 kf = *(const float4*)(qkb + 64 + kl * 4);
        float4 qf = *(const float4*)(qkb + kl * 4);
        float4 sv = svb[0];
        float2 vgv = vgb[vl];
        #pragma unroll
        for (int t = 0; t < CH; t++) {
            float4 kf_n, qf_n, sv_n; float2 vg_n;
            if (t + 1 < CH) {
                kf_n = *(const float4*)(qkb + (t + 1) * 128 + 64 + kl * 4);
                qf_n = *(const float4*)(qkb + (t + 1) * 128 + kl * 4);
                sv_n = svb[t + 1];
                vg_n = vgb[(t + 1) * 16 + vl];
            }

            const float decay = sv.y * rho_hr;
            float2v k0; k0.x = kf.x; k0.y = kf.y;
            float2v k1; k1.x = kf.z; k1.y = kf.w;
            float2v q0; q0.x = qf.x; q0.y = qf.y;
            float2v q1; q1.x = qf.z; q1.y = qf.w;

            float2v t1 = cw0 * sr0 - sw0 * si0;
            float2v u1 = sw0 * sr0 + cw0 * si0;
            float2v t2 = cw1 * sr1 - sw1 * si1;
            float2v u2 = sw1 * sr1 + cw1 * si1;
            float2v d2; d2.x = decay; d2.y = decay;
            float2v rr0 = d2 * t1, rr1 = d2 * t2;
            si0 = d2 * u1; si1 = d2 * u2;

            float2v pk2 = rr0 * k0 + rr1 * k1;
            float2v pq2 = rr0 * q0 + rr1 * q1;
            float pk = pk2.x + pk2.y;
            float pq = pq2.x + pq2.y;
            pk = dpp_add<0xB1>(pk);  pq = dpp_add<0xB1>(pq);   // xor1
            pk = dpp_add<0x4E>(pk);  pq = dpp_add<0x4E>(pq);   // xor2
            pk = dpp_add<0x141>(pk); pq = dpp_add<0x141>(pq);  // xor4
            pk = dpp_add<0x140>(pk); pq = dpp_add<0x140>(pq);  // xor8 (mirror in 16)

            const float sc = sv.x * (vgv.x - pk);
            float2v sc2; sc2.x = sc; sc2.y = sc;
            sr0 = rr0 + sc2 * k0;
            sr1 = rr1 + sc2 * k1;
            const float rp = pq + sc * sv.z;    // = sum(sr_new * q)
            if (kl == 0) obuf[t][vl] = mw * rp * vgv.y;

            kf = kf_n; qf = qf_n; sv = sv_n; vgv = vg_n;
        }

        // --- write staged registers into the other LDS buffer ---
        if (have) {
            #pragma unroll
            for (int rep = 0; rep < 4; rep++) {
                int idx = rep * 256 + tid;
                int t = idx >> 5, sub = idx & 31;
                *(float4*)&qk[nb][t][sub * 4] = g_qk[rep];
            }
            #pragma unroll
            for (int rep = 0; rep < 2; rep++) {
                int idx = rep * 256 + tid;
                int t = idx >> 4, v2 = idx & 15;
                vg[nb][t][v2] = g_vg[rep];
            }
            if (tid < CH)          sc4[nb][tid][0]      = g_sc;
            else if (tid < 2 * CH) sc4[nb][tid - CH][1] = g_sc;
        }
        __syncthreads();
    }
    // final flush
    #pragma unroll
    for (int rep = 0; rep < 2; rep++) {
        int idx = rep * 256 + tid;
        int t = idx >> 4, v2 = idx & 15;
        atomicAdd(dstb + (size_t)(3 * CH + t) * 512 + v2, obuf[t][v2]);
    }
}

// ---------------- Kernel 4: output GEMM, A = fp32 Acomb converted inline ---------------
__global__ __launch_bounds__(256, 2) void out_mfma(const float* __restrict__ Af,
        const ushort* __restrict__ BTb, float* __restrict__ C)
{
    __shared__ ushort sA[2][64][40];
    __shared__ ushort sB[2][64][40];
    const int n0 = blockIdx.x * 64, m0 = blockIdx.y * 64;
    const int tid = threadIdx.x;
    const int lane = tid & 63, w = tid >> 6;
    const int wm = w & 1, wn = w >> 1;
    const int l16 = lane & 15, quad = lane >> 4;
    const int srow = tid >> 2, skq = (tid & 3) * 8;
    const float* Ag = Af + (size_t)(m0 + srow) * 512 + skq;
    const ushort* Bg = BTb + (size_t)(n0 + srow) * 512 + skq;
    float4 fa0 = *(const float4*)Ag;
    float4 fa1 = *(const float4*)(Ag + 4);
    short8 rb = *(const short8*)Bg;
    float4v acc00 = {0,0,0,0}, acc01 = {0,0,0,0}, acc10 = {0,0,0,0}, acc11 = {0,0,0,0};
    for (int kt = 0; kt < 16; kt++) {
        const int cb = kt & 1;
        short8 ra;
        ra[0]=f2bf(fa0.x); ra[1]=f2bf(fa0.y); ra[2]=f2bf(fa0.z); ra[3]=f2bf(fa0.w);
        ra[4]=f2bf(fa1.x); ra[5]=f2bf(fa1.y); ra[6]=f2bf(fa1.z); ra[7]=f2bf(fa1.w);
        *(short8*)&sA[cb][srow][skq] = ra;
        *(short8*)&sB[cb][srow][skq] = rb;
        __syncthreads();
        if (kt + 1 < 16) {
            fa0 = *(const float4*)(Ag + (kt + 1) * 32);
            fa1 = *(const float4*)(Ag + (kt + 1) * 32 + 4);
            rb = *(const short8*)(Bg + (kt + 1) * 32);
        }
        short8 a0 = *(const short8*)&sA[cb][wm * 32 + l16][quad * 8];
        short8 a1 = *(const short8*)&sA[cb][wm * 32 + 16 + l16][quad * 8];
        short8 b0 = *(const short8*)&sB[cb][wn * 32 + l16][quad * 8];
        short8 b1 = *(const short8*)&sB[cb][wn * 32 + 16 + l16][quad * 8];
        acc00 = __builtin_amdgcn_mfma_f32_16x16x32_bf16(a0, b0, acc00, 0, 0, 0);
        acc01 = __builtin_amdgcn_mfma_f32_16x16x32_bf16(a0, b1, acc01, 0, 0, 0);
        acc10 = __builtin_amdgcn_mfma_f32_16x16x32_bf16(a1, b0, acc10, 0, 0, 0);
        acc11 = __builtin_amdgcn_mfma_f32_16x16x32_bf16(a1, b1, acc11, 0, 0, 0);
    }
    const int colb = n0 + wn * 32 + l16;
    const int rowb = m0 + wm * 32 + quad * 4;
    #pragma unroll
    for (int r2 = 0; r2 < 4; r2++) {
        C[(size_t)(rowb + r2) * 1024 + colb] = acc00[r2];
        C[(size_t)(rowb + r2) * 1024 + colb + 16] = acc01[r2];
        C[(size_t)(rowb + 16 + r2) * 1024 + colb] = acc10[r2];
        C[(size_t)(rowb + 16 + r2) * 1024 + colb + 16] = acc11[r2];
    }
}

extern "C" void kernel_launch(void* const* d_in, const int* in_sizes, int n_in,
                              void* d_out, int out_size, void* d_ws, size_t ws_size,
                              hipStream_t stream) {
    const float* x   = (const float*)d_in[0];
    const float* Wq  = (const float*)d_in[1];
    const float* Wk  = (const float*)d_in[2];
    const float* Wv  = (const float*)d_in[3];
    const float* Wb  = (const float*)d_in[4];
    const float* Wtg = (const float*)d_in[5];
    const float* ml  = (const float*)d_in[6];
    const float* ldc = (const float*)d_in[7];
    const float* ols = (const float*)d_in[8];
    const float* Wg  = (const float*)d_in[9];
    const float* Wo  = (const float*)d_in[10];
    float* out = (float*)d_out;

    float* ws = (float*)d_ws;
    float* proj    = ws;                                 // 557056 f
    float* cosw    = proj + 256 * NPROJ;                 // 4096
    float* sinw    = cosw + 4096;                        // 4096
    float* rho     = sinw + 4096;                        // 64
    float* modew   = rho + 64;                           // 64
    ushort* xb     = (ushort*)(modew + 64);              // 262144 us = 131072 f
    ushort* wotb   = (ushort*)((float*)xb + 131072);     // 524288 us = 262144 f
    float*  Acomb  = (float*)wotb + 262144;              // 131072 f
    ushort* wtb    = (ushort*)(Acomb + 131072);          // 2228224 us = 1114112 f

    prep_kernel<<<784, 256, 0, stream>>>(x, Wq, Wk, Wv, Wb, Wtg, Wg, Wo,
                                         ml, ldc, ols, cosw, sinw, rho, modew,
                                         xb, wtb, wotb, Acomb);
    proj_mfma<<<dim3(34, 4), 256, 0, stream>>>(xb, wtb, proj);
    scan_kernel<<<512, 256, 0, stream>>>(proj, cosw, sinw, rho, modew, Acomb);
    out_mfma<<<dim3(16, 4), 256, 0, stream>>>(Acomb, wotb, out);
}